// Round 7
// baseline (624.199 us; speedup 1.0000x reference)
//
#include <hip/hip_runtime.h>
#include <stdint.h>

// ---------- types ----------
typedef __bf16 bf16x8 __attribute__((ext_vector_type(8)));
typedef float  f32x4  __attribute__((ext_vector_type(4)));
typedef const void __attribute__((address_space(1))) gv_t;
typedef void __attribute__((address_space(3))) sv_t;

static __device__ __forceinline__ unsigned short f2bf(float f) {
  unsigned u = __float_as_uint(f);
  u += 0x7fffu + ((u >> 16) & 1u);  // RNE
  return (unsigned short)(u >> 16);
}
static __device__ __forceinline__ float bf2f(unsigned short h) {
  return __uint_as_float(((unsigned)h) << 16);
}
static __device__ __forceinline__ void gload16(const void* g, void* l) {
  __builtin_amdgcn_global_load_lds((gv_t*)g, (sv_t*)l, 16, 0, 0);
}

// ---------- utility ----------
__global__ void k_sentinel(float* out, int n, float val) {
  int t = blockIdx.x * 256 + threadIdx.x;
  if (t < n) out[t] = val;
}
__global__ void k_zero(int* p, int n) {
  int t = blockIdx.x * 256 + threadIdx.x;
  if (t < n) p[t] = 0;
}

// ---------- edge dtype detect: int64 => high 32b words are all 0 ----------
__global__ void k_detect(const int* ei, int* flag) {
  if (blockIdx.x == 0 && threadIdx.x == 0) {
    int nz = 0;
    for (int t = 0; t < 256; ++t) nz += (ei[2 * t + 1] != 0);
    *flag = (nz == 0) ? 1 : 0;  // 1 = int64 layout
  }
}

// ---------- CSR build ----------
__global__ void k_degree(const int* ei, int E, const int* flag, int* deg) {
  int t = blockIdx.x * 256 + threadIdx.x;
  if (t < E) {
    int d = (*flag) ? ei[2 * (E + t)] : ei[E + t];
    atomicAdd(&deg[d], 1);
  }
}
__global__ void k_scan(const int* deg, int* rp, int* cur, int n) {
  __shared__ int ssum[256];
  int t = threadIdx.x;
  int chunk = (n + 255) >> 8;
  int lo = t * chunk, hi = min(lo + chunk, n);
  int s = 0;
  for (int i = lo; i < hi; ++i) s += deg[i];
  ssum[t] = s;
  __syncthreads();
  if (t == 0) {
    int run = 0;
    for (int i = 0; i < 256; ++i) { int v = ssum[i]; ssum[i] = run; run += v; }
  }
  __syncthreads();
  int run = ssum[t];
  for (int i = lo; i < hi; ++i) { rp[i] = run; cur[i] = run; run += deg[i]; }
  if (t == 255) rp[n] = run;
}
__global__ void k_fill(const int* ei, int E, const int* flag, int* cur, int* col) {
  int t = blockIdx.x * 256 + threadIdx.x;
  if (t < E) {
    int f = *flag;
    int s = f ? ei[2 * t] : ei[t];
    int d = f ? ei[2 * (E + t)] : ei[E + t];
    int p = atomicAdd(&cur[d], 1);
    col[p] = s;
  }
}

// ---------- x (f32) -> xm root half (bf16), row stride 1024 ----------
__global__ void k_cvtx(const float4* __restrict__ in, ushort4* __restrict__ xm, int total4) {
  int t = blockIdx.x * 256 + threadIdx.x;
  if (t < total4) {
    int row = t >> 7, c = t & 127;  // 128 ushort4 = 512 feats
    float4 v = in[t];
    xm[(size_t)row * 256 + c] = make_ushort4(f2bf(v.x), f2bf(v.y), f2bf(v.z), f2bf(v.w));
  }
}

// ---------- weight transpose+convert: Wt[n*ld + kofs + k] = bf16(W[k][n]) ----------
__global__ void k_transW(const float* W, unsigned short* Wt, int K, int N, int ld, int kofs) {
  __shared__ float tile[32][33];
  int tx = threadIdx.x & 31, ty = threadIdx.x >> 5;  // 32 x 8
  int n0 = blockIdx.x << 5, k0 = blockIdx.y << 5;
#pragma unroll
  for (int r = 0; r < 4; ++r)
    tile[ty + r * 8][tx] = W[(size_t)(k0 + ty + r * 8) * N + n0 + tx];
  __syncthreads();
#pragma unroll
  for (int r = 0; r < 4; ++r)
    Wt[(size_t)(n0 + ty + r * 8) * ld + kofs + k0 + tx] = f2bf(tile[tx][ty + r * 8]);
}

// ---------- mean aggregation into xm's mean half (cols 512..1023) ----------
__global__ void k_agg(ushort4* __restrict__ xm, const int* __restrict__ rp,
                      const int* __restrict__ col) {
  int i = blockIdx.x;
  int s = rp[i], e = rp[i + 1];
  float inv = 1.0f / (float)max(e - s, 1);
  int f = threadIdx.x;  // 0..127 covers 512 feats
  float4 a = make_float4(0.f, 0.f, 0.f, 0.f);
  for (int n = s; n < e; ++n) {
    ushort4 v = xm[(size_t)col[n] * 256 + f];
    a.x += bf2f(v.x); a.y += bf2f(v.y); a.z += bf2f(v.z); a.w += bf2f(v.w);
  }
  xm[(size_t)i * 256 + 128 + f] =
      make_ushort4(f2bf(a.x * inv), f2bf(a.y * inv), f2bf(a.z * inv), f2bf(a.w * inv));
}

// ================= 256x256 GEMM, fragment-reuse schedule (bf16, f32 acc) ====
// 512 thr = 8 waves (2r x 4c); per-wave C = 128x64 as 8 m-frags x 4 n-frags.
// m-frag row = m*32 + wr*16 + (lane&15); n-frag col = n*64 + wc*16 + (lane&15)
// LDS: 2 bufs x (A 256x64 + B 256x64) bf16 = 128 KiB, XOR-swizzled slots.
// Per K-step iter: lgkm(0)+bar (WAR) -> STAGE 8 into nxt -> vmcnt(8) -> bar
// -> 24 ds_read_b128 + 64 MFMA with a sched_group_barrier-pinned interleave:
// 12 reads, then q00's 16 MFMA overlapped with b1's 4 reads, q01's 16 MFMA
// overlapped with a1's 8 reads, then 32 MFMA. r6 measured cyc/iter == the
// SUM of MFMA (2483) and LDS (2304) pipe time -> emission was serialized;
// this pins the overlap (T19, applied in the regime where it matters).
template <bool RELU, bool BIAS>
__global__ __launch_bounds__(512, 1) void k_gemm256(
    const unsigned short* __restrict__ A, const unsigned short* __restrict__ B,
    const float* __restrict__ bias, unsigned short* __restrict__ outp,
    int Mreal, int N, int K, int bnShift) {
  __shared__ __align__(16) unsigned short lds[2][2][256 * 64];

  const int tid = threadIdx.x;
  const int lane = tid & 63;
  const int wq = tid >> 6;   // 0..7
  const int wr = wq >> 2;    // 0..1
  const int wc = wq & 3;     // 0..3

  // bijective XCD swizzle (m204): bn fastest within an XCD's contiguous chunk
  const int nwg = gridDim.x;
  const int q8 = nwg >> 3, r8 = nwg & 7;
  const int xcd = blockIdx.x & 7, idx = blockIdx.x >> 3;
  const int wg = (xcd < r8 ? xcd * (q8 + 1) : r8 * (q8 + 1) + (xcd - r8) * q8) + idx;
  const int bn = wg & ((1 << bnShift) - 1);
  const int bm = wg >> bnShift;

  const unsigned short* Ap = A + (size_t)bm * 256 * K;
  const unsigned short* Bp = B + (size_t)bn * 256 * K;
  const int sl8 = ((lane & 7) ^ (lane >> 3)) * 8;  // pre-swizzled source col (elems)
  const int rsub = wq * 8 + (lane >> 3);           // row within a 64-row issue

#define STAGE_A(BUF, I, K0)                                            \
  gload16(Ap + (size_t)((I) * 64 + rsub) * K + (K0) + sl8,             \
          (char*)&lds[BUF][0][0] + ((I) * 64 + wq * 8) * 128)
#define STAGE_B(BUF, I, K0)                                            \
  gload16(Bp + (size_t)((I) * 64 + rsub) * K + (K0) + sl8,             \
          (char*)&lds[BUF][1][0] + ((I) * 64 + wq * 8) * 128)
#define VMCNT(NUM) asm volatile("s_waitcnt vmcnt(" #NUM ")" ::: "memory")

  f32x4 acc[8][4];
#pragma unroll
  for (int m = 0; m < 8; ++m)
#pragma unroll
    for (int n = 0; n < 4; ++n) acc[m][n] = (f32x4){0.f, 0.f, 0.f, 0.f};

// load A-frag array for quad QA from buf CUR: 8x ds_read_b128
#define LOAD_AFR(DST, CUR, QA)                                                          \
  do {                                                                                  \
    const char* baseA = (const char*)&lds[CUR][0][0];                                   \
    _Pragma("unroll") for (int mm = 0; mm < 4; ++mm) {                                  \
      const int rr = ((QA) * 4 + mm) * 32 + wr * 16 + (lane & 15);                      \
      _Pragma("unroll") for (int kk = 0; kk < 2; ++kk)                                  \
          DST[mm][kk] = *(const bf16x8*)(baseA + rr * 128 +                             \
                                         (((kk * 4 + (lane >> 4)) ^ (lane & 7)) << 4)); \
    }                                                                                   \
  } while (0)
// load B-frag array for quad QB from buf CUR: 4x ds_read_b128
#define LOAD_BFR(DST, CUR, QB)                                                          \
  do {                                                                                  \
    const char* baseB = (const char*)&lds[CUR][1][0];                                   \
    _Pragma("unroll") for (int nn = 0; nn < 2; ++nn) {                                  \
      const int cc = ((QB) * 2 + nn) * 64 + wc * 16 + (lane & 15);                      \
      _Pragma("unroll") for (int kk = 0; kk < 2; ++kk)                                  \
          DST[nn][kk] = *(const bf16x8*)(baseB + cc * 128 +                             \
                                         (((kk * 4 + (lane >> 4)) ^ (lane & 7)) << 4)); \
    }                                                                                   \
  } while (0)
// 16 MFMA for quad (QA,QB)
#define MFMA_Q(QA, QB, AFR, BFR)                                                        \
  do {                                                                                  \
    _Pragma("unroll") for (int mm = 0; mm < 4; ++mm)                                    \
        _Pragma("unroll") for (int nn = 0; nn < 2; ++nn)                                \
            _Pragma("unroll") for (int kk = 0; kk < 2; ++kk)                            \
                acc[(QA) * 4 + mm][(QB) * 2 + nn] =                                     \
                    __builtin_amdgcn_mfma_f32_16x16x32_bf16(                            \
                        AFR[mm][kk], BFR[nn][kk], acc[(QA) * 4 + mm][(QB) * 2 + nn],    \
                        0, 0, 0);                                                       \
  } while (0)
#define SGB(MASK, N_) __builtin_amdgcn_sched_group_barrier(MASK, N_, 0)

  // prologue: stage K-step 0 into buf0 (8 loads/wave)
  STAGE_A(0, 0, 0); STAGE_A(0, 1, 0);
  STAGE_B(0, 0, 0); STAGE_B(0, 1, 0);
  STAGE_B(0, 2, 0); STAGE_B(0, 3, 0);
  STAGE_A(0, 2, 0); STAGE_A(0, 3, 0);

  const int nt = K >> 6;
#pragma unroll 1
  for (int t = 0; t < nt; ++t) {
    const int cur = t & 1, nxt = cur ^ 1;
    const int k1 = (t + 1) << 6;
    // P1: my prev-iter ds_reads retired; collective -> safe to restage nxt
    asm volatile("s_waitcnt lgkmcnt(0)" ::: "memory");
    __builtin_amdgcn_s_barrier();
    if (t < nt - 1) {
      STAGE_A(nxt, 0, k1); STAGE_A(nxt, 1, k1);
      STAGE_B(nxt, 0, k1); STAGE_B(nxt, 1, k1);
      STAGE_B(nxt, 2, k1); STAGE_B(nxt, 3, k1);
      STAGE_A(nxt, 2, k1); STAGE_A(nxt, 3, k1);
      VMCNT(8);  // cur's 8 retired; nxt's 8 stay in flight across this iter
    } else {
      VMCNT(0);
    }
    // P2: cur-tile-ready, collective
    __builtin_amdgcn_s_barrier();

    __builtin_amdgcn_s_setprio(1);
    {
      bf16x8 a0[4][2], a1[4][2], b0[2][2], b1[2][2];
      LOAD_AFR(a0, cur, 0);
      LOAD_BFR(b0, cur, 0);
      LOAD_BFR(b1, cur, 1);
      LOAD_AFR(a1, cur, 1);
      MFMA_Q(0, 0, a0, b0);
      MFMA_Q(0, 1, a0, b1);
      MFMA_Q(1, 1, a1, b1);
      MFMA_Q(1, 0, a1, b0);
      // pinned interleave: 12 reads (a0,b0); q00 MFMA // b1 reads;
      // q01 MFMA // a1 reads; remaining 32 MFMA.
      SGB(0x100, 12);
      SGB(0x8, 8); SGB(0x100, 2);
      SGB(0x8, 8); SGB(0x100, 2);
      SGB(0x8, 8); SGB(0x100, 4);
      SGB(0x8, 8); SGB(0x100, 4);
      SGB(0x8, 32);
    }
    __builtin_amdgcn_s_setprio(0);
  }

  // epilogue: D col = lane&15, row = (lane>>4)*4 + r  (m89-verified mapping)
  const int row0 = bm * 256 + wr * 16 + ((lane >> 4) << 2);
  const int col0 = bn * 256 + wc * 16 + (lane & 15);
#pragma unroll
  for (int m = 0; m < 8; ++m) {
#pragma unroll
    for (int n = 0; n < 4; ++n) {
      const int col = col0 + n * 64;
      float bb = BIAS ? bias[col] : 0.f;
#pragma unroll
      for (int r = 0; r < 4; ++r) {
        int row = row0 + m * 32 + r;
        if (row < Mreal) {
          float v = acc[m][n][r] + bb;
          if (RELU) v = fmaxf(v, 0.f);
          outp[(size_t)row * N + col] = f2bf(v);
        }
      }
    }
  }
#undef SGB
#undef MFMA_Q
#undef LOAD_BFR
#undef LOAD_AFR
#undef VMCNT
#undef STAGE_A
#undef STAGE_B
}

// ---------- legacy 128x128 GEMM (proven) for the tiny layer-3 matmul ----------
template <int NF, bool TWO, bool RELU, bool BIAS>
__global__ __launch_bounds__(256) void k_gemm(
    const unsigned short* __restrict__ Am, const unsigned short* __restrict__ Ar,
    const unsigned short* __restrict__ Bl, const unsigned short* __restrict__ Br,
    const float* __restrict__ bias, unsigned short* __restrict__ outp, int N, int K) {
  constexpr int BN = NF * 32;
  __shared__ __align__(16) unsigned short lds[(128 + BN) * 64];
  unsigned short* ldsA = lds;
  unsigned short* ldsB = lds + 128 * 64;

  const int tid = threadIdx.x;
  const int lane = tid & 63;
  const int w = tid >> 6;
  const int wr = w >> 1, wc = w & 1;

  f32x4 zero = {0.f, 0.f, 0.f, 0.f};
  f32x4 acc[4][NF];
#pragma unroll
  for (int m = 0; m < 4; ++m)
#pragma unroll
    for (int n = 0; n < NF; ++n) acc[m][n] = zero;

  const int bm = blockIdx.x, bn = blockIdx.y;
  const int sl_st = (lane & 7) ^ (lane >> 3);

#pragma unroll 1
  for (int pass = 0; pass < (TWO ? 2 : 1); ++pass) {
    const unsigned short* A = (TWO && pass) ? Ar : Am;
    const unsigned short* B = (TWO && pass) ? Br : Bl;
    A += (size_t)bm * 128 * K;
    B += (size_t)bn * BN * K;
#pragma unroll 1
    for (int k0 = 0; k0 < K; k0 += 64) {
      __syncthreads();
#pragma unroll
      for (int q = 0; q < 4; ++q) {
        int rowi = (w * 4 + q) * 8 + (lane >> 3);
        gload16(A + (size_t)rowi * K + k0 + sl_st * 8, (char*)ldsA + (w * 4 + q) * 1024);
      }
#pragma unroll
      for (int q = 0; q < NF; ++q) {
        int rowi = (w * NF + q) * 8 + (lane >> 3);
        gload16(B + (size_t)rowi * K + k0 + sl_st * 8, (char*)ldsB + (w * NF + q) * 1024);
      }
      __syncthreads();
#pragma unroll
      for (int kk = 0; kk < 2; ++kk) {
        int sw = (((kk * 4 + (lane >> 4)) ^ (lane & 7)) << 4);
        bf16x8 af[4], bfr[NF];
#pragma unroll
        for (int m = 0; m < 4; ++m) {
          int r = wr * 64 + m * 16 + (lane & 15);
          af[m] = *(const bf16x8*)((const char*)ldsA + r * 128 + sw);
        }
#pragma unroll
        for (int n = 0; n < NF; ++n) {
          int c = wc * (BN / 2) + n * 16 + (lane & 15);
          bfr[n] = *(const bf16x8*)((const char*)ldsB + c * 128 + sw);
        }
#pragma unroll
        for (int m = 0; m < 4; ++m)
#pragma unroll
          for (int n = 0; n < NF; ++n)
            acc[m][n] = __builtin_amdgcn_mfma_f32_16x16x32_bf16(af[m], bfr[n], acc[m][n], 0, 0, 0);
      }
    }
  }

  const int row0 = bm * 128 + wr * 64;
  const int col0 = bn * BN + wc * (BN / 2);
#pragma unroll
  for (int m = 0; m < 4; ++m) {
#pragma unroll
    for (int n = 0; n < NF; ++n) {
      int col = col0 + n * 16 + (lane & 15);
      float bb = BIAS ? bias[col] : 0.f;
#pragma unroll
      for (int r = 0; r < 4; ++r) {
        int row = row0 + m * 16 + ((lane >> 4) << 2) + r;
        float v = acc[m][n][r] + bb;
        if (RELU) v = fmaxf(v, 0.f);
        outp[(size_t)row * N + col] = f2bf(v);
      }
    }
  }
}

// ---------- layer2 combine: h2 = relu(mean_j Z2l[j] + Z2r[i] + b2) ----------
__global__ void k_combine2(const ushort4* __restrict__ Z2, const int* __restrict__ rp,
                           const int* __restrict__ col, const float* __restrict__ bias,
                           ushort4* __restrict__ h2) {
  int i = blockIdx.x;
  int s = rp[i], e = rp[i + 1];
  float inv = 1.0f / (float)max(e - s, 1);
  int f = threadIdx.x;  // 0..255 covers Z2l (1024 feats)
  float4 a = make_float4(0.f, 0.f, 0.f, 0.f);
  float4 b = make_float4(0.f, 0.f, 0.f, 0.f);
  int n = s;
  for (; n + 1 < e; n += 2) {
    int j0 = col[n], j1 = col[n + 1];
    ushort4 v0 = Z2[(size_t)j0 * 512 + f];
    ushort4 v1 = Z2[(size_t)j1 * 512 + f];
    a.x += bf2f(v0.x); a.y += bf2f(v0.y); a.z += bf2f(v0.z); a.w += bf2f(v0.w);
    b.x += bf2f(v1.x); b.y += bf2f(v1.y); b.z += bf2f(v1.z); b.w += bf2f(v1.w);
  }
  if (n < e) {
    ushort4 v0 = Z2[(size_t)col[n] * 512 + f];
    a.x += bf2f(v0.x); a.y += bf2f(v0.y); a.z += bf2f(v0.z); a.w += bf2f(v0.w);
  }
  a.x += b.x; a.y += b.y; a.z += b.z; a.w += b.w;
  ushort4 r = Z2[(size_t)i * 512 + 256 + f];
  float4 b4 = ((const float4*)bias)[f];
  float o0 = fmaxf(a.x * inv + bf2f(r.x) + b4.x, 0.f);
  float o1 = fmaxf(a.y * inv + bf2f(r.y) + b4.y, 0.f);
  float o2 = fmaxf(a.z * inv + bf2f(r.z) + b4.z, 0.f);
  float o3 = fmaxf(a.w * inv + bf2f(r.w) + b4.w, 0.f);
  h2[(size_t)i * 256 + f] = make_ushort4(f2bf(o0), f2bf(o1), f2bf(o2), f2bf(o3));
}

// ---------- layer3 combine + log_softmax: one wave per node ----------
__global__ void k_combine3(const unsigned short* __restrict__ Z3, const int* __restrict__ rp,
                           const int* __restrict__ col, const float* __restrict__ bias,
                           float* __restrict__ out) {
  int i = blockIdx.x * 4 + (threadIdx.x >> 6);
  int c = threadIdx.x & 63;
  int s = rp[i], e = rp[i + 1];
  float inv = 1.0f / (float)max(e - s, 1);
  float a = 0.f;
  for (int n = s; n < e; ++n) a += bf2f(Z3[(size_t)col[n] * 128 + c]);
  float v = a * inv + bf2f(Z3[(size_t)i * 128 + 64 + c]) + bias[c];
  float m = v;
#pragma unroll
  for (int o = 1; o < 64; o <<= 1) m = fmaxf(m, __shfl_xor(m, o, 64));
  float t = expf(v - m);
  float sum = t;
#pragma unroll
  for (int o = 1; o < 64; o <<= 1) sum += __shfl_xor(sum, o, 64);
  out[(size_t)i * 64 + c] = (v - m) - logf(sum);
}

// ---------- launch ----------
extern "C" void kernel_launch(void* const* d_in, const int* in_sizes, int n_in,
                              void* d_out, int out_size, void* d_ws, size_t ws_size,
                              hipStream_t stream) {
  const float* x   = (const float*)d_in[0];
  const int*   ei  = (const int*)d_in[1];
  const float* W1l = (const float*)d_in[2];
  const float* b1  = (const float*)d_in[3];
  const float* W1r = (const float*)d_in[4];
  const float* W2l = (const float*)d_in[5];
  const float* b2  = (const float*)d_in[6];
  const float* W2r = (const float*)d_in[7];
  const float* W3l = (const float*)d_in[8];
  const float* b3  = (const float*)d_in[9];
  const float* W3r = (const float*)d_in[10];

  const int Nn = 16000;
  const int E = in_sizes[1] / 2;

  char* p = (char*)d_ws;
  auto carve = [&](size_t bytes) {
    char* r = p;
    p += (bytes + 255) & ~(size_t)255;
    return r;
  };
  int* deg    = (int*)carve((size_t)Nn * 4);
  int* rp     = (int*)carve((size_t)(Nn + 1) * 4);
  int* cur    = (int*)carve((size_t)Nn * 4);
  int* flag   = (int*)carve(4);
  int* colidx = (int*)carve((size_t)E * 4);
  unsigned short* Wb = (unsigned short*)carve((size_t)2048 * 4096 * 2);  // weights, reused
  unsigned short* xm = (unsigned short*)carve((size_t)Nn * 1024 * 2);    // [root|mean]; later h2
  unsigned short* h1 = (unsigned short*)carve((size_t)Nn * 4096 * 2);
  unsigned short* Z2 = (unsigned short*)carve((size_t)Nn * 2048 * 2);
  unsigned short* Z3 = (unsigned short*)carve((size_t)Nn * 128 * 2);
  unsigned short* h2 = xm;  // xm dead after GEMM1

  size_t need = (size_t)(p - (char*)d_ws);
  if (ws_size < need) {
    k_sentinel<<<(out_size + 255) / 256, 256, 0, stream>>>((float*)d_out, out_size,
                                                           (float)(ws_size >> 20));
    return;
  }

  // CSR
  k_zero<<<(Nn + 255) / 256, 256, 0, stream>>>(deg, Nn);
  k_detect<<<1, 64, 0, stream>>>(ei, flag);
  k_degree<<<(E + 255) / 256, 256, 0, stream>>>(ei, E, flag, deg);
  k_scan<<<1, 256, 0, stream>>>(deg, rp, cur, Nn);
  k_fill<<<(E + 255) / 256, 256, 0, stream>>>(ei, E, flag, cur, colidx);

  // layer 1: A = [root | mean] (K=1024), B1 = [W1r^T | W1l^T] (4096 x 1024)
  k_cvtx<<<(Nn * 128 + 255) / 256, 256, 0, stream>>>((const float4*)x, (ushort4*)xm, Nn * 128);
  k_transW<<<dim3(4096 / 32, 512 / 32), 256, 0, stream>>>(W1r, Wb, 512, 4096, 1024, 0);
  k_transW<<<dim3(4096 / 32, 512 / 32), 256, 0, stream>>>(W1l, Wb, 512, 4096, 1024, 512);
  k_agg<<<Nn, 128, 0, stream>>>((ushort4*)xm, rp, colidx);
  k_gemm256<true, true><<<63 * 16, 512, 0, stream>>>(xm, Wb, b1, h1, Nn, 4096, 1024, 4);

  // layer 2 (post-agg): Z2 = h1 @ [W2l^T ; W2r^T]  (N=2048, K=4096)
  k_transW<<<dim3(1024 / 32, 4096 / 32), 256, 0, stream>>>(W2l, Wb, 4096, 1024, 4096, 0);
  k_transW<<<dim3(1024 / 32, 4096 / 32), 256, 0, stream>>>(W2r, Wb + (size_t)1024 * 4096, 4096,
                                                           1024, 4096, 0);
  k_gemm256<false, false><<<63 * 8, 512, 0, stream>>>(h1, Wb, nullptr, Z2, Nn, 2048, 4096, 3);
  k_combine2<<<Nn, 256, 0, stream>>>((const ushort4*)Z2, rp, colidx, b2, (ushort4*)h2);

  // layer 3 (post-agg, tiny): Z3 = h2 @ [W3l^T ; W3r^T]  (N=128, K=1024)
  k_transW<<<dim3(64 / 32, 1024 / 32), 256, 0, stream>>>(W3l, Wb, 1024, 64, 1024, 0);
  k_transW<<<dim3(64 / 32, 1024 / 32), 256, 0, stream>>>(W3r, Wb + (size_t)64 * 1024, 1024, 64,
                                                         1024, 0);
  k_gemm<2, false, false, false><<<dim3(125, 2), 256, 0, stream>>>(h2, nullptr, Wb, nullptr,
                                                                   nullptr, Z3, 128, 1024);
  k_combine3<<<Nn / 4, 256, 0, stream>>>(Z3, rp, colidx, b3, (float*)d_out);

  (void)n_in; (void)out_size;
}

// Round 8
// 590.035 us; speedup vs baseline: 1.0579x; 1.0579x over previous
//
#include <hip/hip_runtime.h>
#include <stdint.h>

// ---------- types ----------
typedef __bf16 bf16x8 __attribute__((ext_vector_type(8)));
typedef float  f32x4  __attribute__((ext_vector_type(4)));
typedef const void __attribute__((address_space(1))) gv_t;
typedef void __attribute__((address_space(3))) sv_t;

static __device__ __forceinline__ unsigned short f2bf(float f) {
  unsigned u = __float_as_uint(f);
  u += 0x7fffu + ((u >> 16) & 1u);  // RNE
  return (unsigned short)(u >> 16);
}
static __device__ __forceinline__ float bf2f(unsigned short h) {
  return __uint_as_float(((unsigned)h) << 16);
}
static __device__ __forceinline__ void gload16(const void* g, void* l) {
  __builtin_amdgcn_global_load_lds((gv_t*)g, (sv_t*)l, 16, 0, 0);
}

// ---------- utility ----------
__global__ void k_sentinel(float* out, int n, float val) {
  int t = blockIdx.x * 256 + threadIdx.x;
  if (t < n) out[t] = val;
}
__global__ void k_zero(int* p, int n) {
  int t = blockIdx.x * 256 + threadIdx.x;
  if (t < n) p[t] = 0;
}

// ---------- edge dtype detect: int64 => high 32b words are all 0 ----------
__global__ void k_detect(const int* ei, int* flag) {
  if (blockIdx.x == 0 && threadIdx.x == 0) {
    int nz = 0;
    for (int t = 0; t < 256; ++t) nz += (ei[2 * t + 1] != 0);
    *flag = (nz == 0) ? 1 : 0;  // 1 = int64 layout
  }
}

// ---------- CSR build ----------
__global__ void k_degree(const int* ei, int E, const int* flag, int* deg) {
  int t = blockIdx.x * 256 + threadIdx.x;
  if (t < E) {
    int d = (*flag) ? ei[2 * (E + t)] : ei[E + t];
    atomicAdd(&deg[d], 1);
  }
}
__global__ void k_scan(const int* deg, int* rp, int* cur, int n) {
  __shared__ int ssum[256];
  int t = threadIdx.x;
  int chunk = (n + 255) >> 8;
  int lo = t * chunk, hi = min(lo + chunk, n);
  int s = 0;
  for (int i = lo; i < hi; ++i) s += deg[i];
  ssum[t] = s;
  __syncthreads();
  if (t == 0) {
    int run = 0;
    for (int i = 0; i < 256; ++i) { int v = ssum[i]; ssum[i] = run; run += v; }
  }
  __syncthreads();
  int run = ssum[t];
  for (int i = lo; i < hi; ++i) { rp[i] = run; cur[i] = run; run += deg[i]; }
  if (t == 255) rp[n] = run;
}
__global__ void k_fill(const int* ei, int E, const int* flag, int* cur, int* col) {
  int t = blockIdx.x * 256 + threadIdx.x;
  if (t < E) {
    int f = *flag;
    int s = f ? ei[2 * t] : ei[t];
    int d = f ? ei[2 * (E + t)] : ei[E + t];
    int p = atomicAdd(&cur[d], 1);
    col[p] = s;
  }
}

// ---------- x (f32) -> xm root half (bf16), row stride 1024 ----------
__global__ void k_cvtx(const float4* __restrict__ in, ushort4* __restrict__ xm, int total4) {
  int t = blockIdx.x * 256 + threadIdx.x;
  if (t < total4) {
    int row = t >> 7, c = t & 127;  // 128 ushort4 = 512 feats
    float4 v = in[t];
    xm[(size_t)row * 256 + c] = make_ushort4(f2bf(v.x), f2bf(v.y), f2bf(v.z), f2bf(v.w));
  }
}

// ---------- weight transpose+convert: Wt[n*ld + kofs + k] = bf16(W[k][n]) ----------
__global__ void k_transW(const float* W, unsigned short* Wt, int K, int N, int ld, int kofs) {
  __shared__ float tile[32][33];
  int tx = threadIdx.x & 31, ty = threadIdx.x >> 5;  // 32 x 8
  int n0 = blockIdx.x << 5, k0 = blockIdx.y << 5;
#pragma unroll
  for (int r = 0; r < 4; ++r)
    tile[ty + r * 8][tx] = W[(size_t)(k0 + ty + r * 8) * N + n0 + tx];
  __syncthreads();
#pragma unroll
  for (int r = 0; r < 4; ++r)
    Wt[(size_t)(n0 + ty + r * 8) * ld + kofs + k0 + tx] = f2bf(tile[tx][ty + r * 8]);
}

// ---------- mean aggregation into xm's mean half (cols 512..1023) ----------
__global__ void k_agg(ushort4* __restrict__ xm, const int* __restrict__ rp,
                      const int* __restrict__ col) {
  int i = blockIdx.x;
  int s = rp[i], e = rp[i + 1];
  float inv = 1.0f / (float)max(e - s, 1);
  int f = threadIdx.x;  // 0..127 covers 512 feats
  float4 a = make_float4(0.f, 0.f, 0.f, 0.f);
  for (int n = s; n < e; ++n) {
    ushort4 v = xm[(size_t)col[n] * 256 + f];
    a.x += bf2f(v.x); a.y += bf2f(v.y); a.z += bf2f(v.z); a.w += bf2f(v.w);
  }
  xm[(size_t)i * 256 + 128 + f] =
      make_ushort4(f2bf(a.x * inv), f2bf(a.y * inv), f2bf(a.z * inv), f2bf(a.w * inv));
}

// ================= 256x256 GEMM, carried-quad software pipeline =============
// 512 thr = 8 waves (2r x 4c); per-wave C = 128x64 as 8 m-frags x 4 n-frags.
// m-frag row = m*32 + wr*16 + (lane&15); n-frag col = n*64 + wc*16 + (lane&15)
// LDS: 2 bufs x (A 256x64 + B 256x64) bf16 = 128 KiB, XOR-swizzled slots.
// r6/r7 measured cyc/iter == SUM of LDS (2304) + MFMA (2483) pipe time: the
// two per-iter barriers lock both waves/SIMD into the same phase, so reads
// never overlap MFMAs. Fix: carry quad-0 fragments (a0,b0) across the
// backedge so every MFMA cluster's inputs are resident BEFORE its phase:
//   A: read a1,b1[cur]   B: q00(a0,b0)          <- B hides A's reads
//   C: lgkm(0)+bar       D: stage t+2 -> cur    <- WAR safe via C
//   E: q10(a1,b0), q01(a0,b1)                   <- a0,b0 die here
//   F: vmcnt(8)+bar      G: read a0,b0[nxt]     <- t+1 collective-ready
//   H: q11(a1,b1)                               <- H hides G's reads
// Budget note: 8 waves x 128KiB LDS => 2 waves/SIMD => 256 unified regs/wave;
// acc = 128 AGPR => hard 128 arch-VGPR cap. Peak frag liveness here ~96.
template <bool RELU, bool BIAS>
__global__ __launch_bounds__(512, 1) void k_gemm256(
    const unsigned short* __restrict__ A, const unsigned short* __restrict__ B,
    const float* __restrict__ bias, unsigned short* __restrict__ outp,
    int Mreal, int N, int K, int bnShift) {
  __shared__ __align__(16) unsigned short lds[2][2][256 * 64];

  const int tid = threadIdx.x;
  const int lane = tid & 63;
  const int wq = tid >> 6;   // 0..7
  const int wr = wq >> 2;    // 0..1
  const int wc = wq & 3;     // 0..3

  // bijective XCD swizzle (m204): bn fastest within an XCD's contiguous chunk
  const int nwg = gridDim.x;
  const int q8 = nwg >> 3, r8 = nwg & 7;
  const int xcd = blockIdx.x & 7, idx = blockIdx.x >> 3;
  const int wg = (xcd < r8 ? xcd * (q8 + 1) : r8 * (q8 + 1) + (xcd - r8) * q8) + idx;
  const int bn = wg & ((1 << bnShift) - 1);
  const int bm = wg >> bnShift;

  const unsigned short* Ap = A + (size_t)bm * 256 * K;
  const unsigned short* Bp = B + (size_t)bn * 256 * K;
  const int sl8 = ((lane & 7) ^ (lane >> 3)) * 8;  // pre-swizzled source col (elems)
  const int rsub = wq * 8 + (lane >> 3);           // row within a 64-row issue

#define STAGE_A(BUF, I, K0)                                            \
  gload16(Ap + (size_t)((I) * 64 + rsub) * K + (K0) + sl8,             \
          (char*)&lds[BUF][0][0] + ((I) * 64 + wq * 8) * 128)
#define STAGE_B(BUF, I, K0)                                            \
  gload16(Bp + (size_t)((I) * 64 + rsub) * K + (K0) + sl8,             \
          (char*)&lds[BUF][1][0] + ((I) * 64 + wq * 8) * 128)
#define VMCNT(NUM) asm volatile("s_waitcnt vmcnt(" #NUM ")" ::: "memory")

  f32x4 acc[8][4];
#pragma unroll
  for (int m = 0; m < 8; ++m)
#pragma unroll
    for (int n = 0; n < 4; ++n) acc[m][n] = (f32x4){0.f, 0.f, 0.f, 0.f};

// load A-frag array for quad QA from buf CUR: 8x ds_read_b128
#define LOAD_AFR(DST, CUR, QA)                                                          \
  do {                                                                                  \
    const char* baseA = (const char*)&lds[CUR][0][0];                                   \
    _Pragma("unroll") for (int mm = 0; mm < 4; ++mm) {                                  \
      const int rr = ((QA) * 4 + mm) * 32 + wr * 16 + (lane & 15);                      \
      _Pragma("unroll") for (int kk = 0; kk < 2; ++kk)                                  \
          DST[mm][kk] = *(const bf16x8*)(baseA + rr * 128 +                             \
                                         (((kk * 4 + (lane >> 4)) ^ (lane & 7)) << 4)); \
    }                                                                                   \
  } while (0)
// load B-frag array for quad QB from buf CUR: 4x ds_read_b128
#define LOAD_BFR(DST, CUR, QB)                                                          \
  do {                                                                                  \
    const char* baseB = (const char*)&lds[CUR][1][0];                                   \
    _Pragma("unroll") for (int nn = 0; nn < 2; ++nn) {                                  \
      const int cc = ((QB) * 2 + nn) * 64 + wc * 16 + (lane & 15);                      \
      _Pragma("unroll") for (int kk = 0; kk < 2; ++kk)                                  \
          DST[nn][kk] = *(const bf16x8*)(baseB + cc * 128 +                             \
                                         (((kk * 4 + (lane >> 4)) ^ (lane & 7)) << 4)); \
    }                                                                                   \
  } while (0)
// 16 MFMA for quad (QA,QB)
#define MFMA_Q(QA, QB, AFR, BFR)                                                        \
  do {                                                                                  \
    _Pragma("unroll") for (int mm = 0; mm < 4; ++mm)                                    \
        _Pragma("unroll") for (int nn = 0; nn < 2; ++nn)                                \
            _Pragma("unroll") for (int kk = 0; kk < 2; ++kk)                            \
                acc[(QA) * 4 + mm][(QB) * 2 + nn] =                                     \
                    __builtin_amdgcn_mfma_f32_16x16x32_bf16(                            \
                        AFR[mm][kk], BFR[nn][kk], acc[(QA) * 4 + mm][(QB) * 2 + nn],    \
                        0, 0, 0);                                                       \
  } while (0)

  // prologue: stage tile0 -> buf0, tile1 -> buf1; wait tile0; read quad-0 frags
  STAGE_A(0, 0, 0); STAGE_A(0, 1, 0);
  STAGE_B(0, 0, 0); STAGE_B(0, 1, 0);
  STAGE_B(0, 2, 0); STAGE_B(0, 3, 0);
  STAGE_A(0, 2, 0); STAGE_A(0, 3, 0);
  STAGE_A(1, 0, 64); STAGE_A(1, 1, 64);
  STAGE_B(1, 0, 64); STAGE_B(1, 1, 64);
  STAGE_B(1, 2, 64); STAGE_B(1, 3, 64);
  STAGE_A(1, 2, 64); STAGE_A(1, 3, 64);
  VMCNT(8);  // tile0 arrived (tile1's 8 still in flight)
  __builtin_amdgcn_s_barrier();

  bf16x8 a0[4][2], b0[2][2], a1[4][2], b1[2][2];
  LOAD_AFR(a0, 0, 0);
  LOAD_BFR(b0, 0, 0);

  const int nt = K >> 6;
#pragma unroll 1
  for (int t = 0; t < nt; ++t) {
    const int cur = t & 1, nxt = cur ^ 1;
    const int k2 = (t + 2) << 6;
    // A: read second-half frags of cur
    LOAD_AFR(a1, cur, 1);
    LOAD_BFR(b1, cur, 1);
    // B: q00 on carried frags (hides A's reads)
    __builtin_amdgcn_s_setprio(1);
    MFMA_Q(0, 0, a0, b0);
    __builtin_amdgcn_s_setprio(0);
    // C: all cur reads done, collective -> cur restage is WAR-safe
    asm volatile("s_waitcnt lgkmcnt(0)" ::: "memory");
    __builtin_amdgcn_s_barrier();
    // D: stage tile t+2 into cur
    if (t + 2 < nt) {
      STAGE_A(cur, 0, k2); STAGE_A(cur, 1, k2);
      STAGE_B(cur, 0, k2); STAGE_B(cur, 1, k2);
      STAGE_B(cur, 2, k2); STAGE_B(cur, 3, k2);
      STAGE_A(cur, 2, k2); STAGE_A(cur, 3, k2);
    }
    // E: q10 + q01 (a0,b0 die here)
    __builtin_amdgcn_s_setprio(1);
    MFMA_Q(1, 0, a1, b0);
    MFMA_Q(0, 1, a0, b1);
    __builtin_amdgcn_s_setprio(0);
    if (t + 1 < nt) {
      // F: tile t+1 collective-ready (keep t+2's 8 loads in flight)
      if (t + 2 < nt) { VMCNT(8); } else { VMCNT(0); }
      __builtin_amdgcn_s_barrier();
      // G: read next tile's quad-0 frags (hidden under H)
      LOAD_AFR(a0, nxt, 0);
      LOAD_BFR(b0, nxt, 0);
    }
    // H: q11
    __builtin_amdgcn_s_setprio(1);
    MFMA_Q(1, 1, a1, b1);
    __builtin_amdgcn_s_setprio(0);
  }

  // epilogue: D col = lane&15, row = (lane>>4)*4 + r  (m89-verified mapping)
  const int row0 = bm * 256 + wr * 16 + ((lane >> 4) << 2);
  const int col0 = bn * 256 + wc * 16 + (lane & 15);
#pragma unroll
  for (int m = 0; m < 8; ++m) {
#pragma unroll
    for (int n = 0; n < 4; ++n) {
      const int col = col0 + n * 64;
      float bb = BIAS ? bias[col] : 0.f;
#pragma unroll
      for (int r = 0; r < 4; ++r) {
        int row = row0 + m * 32 + r;
        if (row < Mreal) {
          float v = acc[m][n][r] + bb;
          if (RELU) v = fmaxf(v, 0.f);
          outp[(size_t)row * N + col] = f2bf(v);
        }
      }
    }
  }
#undef MFMA_Q
#undef LOAD_BFR
#undef LOAD_AFR
#undef VMCNT
#undef STAGE_A
#undef STAGE_B
}

// ---------- legacy 128x128 GEMM (proven) for the tiny layer-3 matmul ----------
template <int NF, bool TWO, bool RELU, bool BIAS>
__global__ __launch_bounds__(256) void k_gemm(
    const unsigned short* __restrict__ Am, const unsigned short* __restrict__ Ar,
    const unsigned short* __restrict__ Bl, const unsigned short* __restrict__ Br,
    const float* __restrict__ bias, unsigned short* __restrict__ outp, int N, int K) {
  constexpr int BN = NF * 32;
  __shared__ __align__(16) unsigned short lds[(128 + BN) * 64];
  unsigned short* ldsA = lds;
  unsigned short* ldsB = lds + 128 * 64;

  const int tid = threadIdx.x;
  const int lane = tid & 63;
  const int w = tid >> 6;
  const int wr = w >> 1, wc = w & 1;

  f32x4 zero = {0.f, 0.f, 0.f, 0.f};
  f32x4 acc[4][NF];
#pragma unroll
  for (int m = 0; m < 4; ++m)
#pragma unroll
    for (int n = 0; n < NF; ++n) acc[m][n] = zero;

  const int bm = blockIdx.x, bn = blockIdx.y;
  const int sl_st = (lane & 7) ^ (lane >> 3);

#pragma unroll 1
  for (int pass = 0; pass < (TWO ? 2 : 1); ++pass) {
    const unsigned short* A = (TWO && pass) ? Ar : Am;
    const unsigned short* B = (TWO && pass) ? Br : Bl;
    A += (size_t)bm * 128 * K;
    B += (size_t)bn * BN * K;
#pragma unroll 1
    for (int k0 = 0; k0 < K; k0 += 64) {
      __syncthreads();
#pragma unroll
      for (int q = 0; q < 4; ++q) {
        int rowi = (w * 4 + q) * 8 + (lane >> 3);
        gload16(A + (size_t)rowi * K + k0 + sl_st * 8, (char*)ldsA + (w * 4 + q) * 1024);
      }
#pragma unroll
      for (int q = 0; q < NF; ++q) {
        int rowi = (w * NF + q) * 8 + (lane >> 3);
        gload16(B + (size_t)rowi * K + k0 + sl_st * 8, (char*)ldsB + (w * NF + q) * 1024);
      }
      __syncthreads();
#pragma unroll
      for (int kk = 0; kk < 2; ++kk) {
        int sw = (((kk * 4 + (lane >> 4)) ^ (lane & 7)) << 4);
        bf16x8 af[4], bfr[NF];
#pragma unroll
        for (int m = 0; m < 4; ++m) {
          int r = wr * 64 + m * 16 + (lane & 15);
          af[m] = *(const bf16x8*)((const char*)ldsA + r * 128 + sw);
        }
#pragma unroll
        for (int n = 0; n < NF; ++n) {
          int c = wc * (BN / 2) + n * 16 + (lane & 15);
          bfr[n] = *(const bf16x8*)((const char*)ldsB + c * 128 + sw);
        }
#pragma unroll
        for (int m = 0; m < 4; ++m)
#pragma unroll
          for (int n = 0; n < NF; ++n)
            acc[m][n] = __builtin_amdgcn_mfma_f32_16x16x32_bf16(af[m], bfr[n], acc[m][n], 0, 0, 0);
      }
    }
  }

  const int row0 = bm * 128 + wr * 64;
  const int col0 = bn * BN + wc * (BN / 2);
#pragma unroll
  for (int m = 0; m < 4; ++m) {
#pragma unroll
    for (int n = 0; n < NF; ++n) {
      int col = col0 + n * 16 + (lane & 15);
      float bb = BIAS ? bias[col] : 0.f;
#pragma unroll
      for (int r = 0; r < 4; ++r) {
        int row = row0 + m * 16 + ((lane >> 4) << 2) + r;
        float v = acc[m][n][r] + bb;
        if (RELU) v = fmaxf(v, 0.f);
        outp[(size_t)row * N + col] = f2bf(v);
      }
    }
  }
}

// ---------- layer2 combine: h2 = relu(mean_j Z2l[j] + Z2r[i] + b2) ----------
__global__ void k_combine2(const ushort4* __restrict__ Z2, const int* __restrict__ rp,
                           const int* __restrict__ col, const float* __restrict__ bias,
                           ushort4* __restrict__ h2) {
  int i = blockIdx.x;
  int s = rp[i], e = rp[i + 1];
  float inv = 1.0f / (float)max(e - s, 1);
  int f = threadIdx.x;  // 0..255 covers Z2l (1024 feats)
  float4 a = make_float4(0.f, 0.f, 0.f, 0.f);
  float4 b = make_float4(0.f, 0.f, 0.f, 0.f);
  int n = s;
  for (; n + 1 < e; n += 2) {
    int j0 = col[n], j1 = col[n + 1];
    ushort4 v0 = Z2[(size_t)j0 * 512 + f];
    ushort4 v1 = Z2[(size_t)j1 * 512 + f];
    a.x += bf2f(v0.x); a.y += bf2f(v0.y); a.z += bf2f(v0.z); a.w += bf2f(v0.w);
    b.x += bf2f(v1.x); b.y += bf2f(v1.y); b.z += bf2f(v1.z); b.w += bf2f(v1.w);
  }
  if (n < e) {
    ushort4 v0 = Z2[(size_t)col[n] * 512 + f];
    a.x += bf2f(v0.x); a.y += bf2f(v0.y); a.z += bf2f(v0.z); a.w += bf2f(v0.w);
  }
  a.x += b.x; a.y += b.y; a.z += b.z; a.w += b.w;
  ushort4 r = Z2[(size_t)i * 512 + 256 + f];
  float4 b4 = ((const float4*)bias)[f];
  float o0 = fmaxf(a.x * inv + bf2f(r.x) + b4.x, 0.f);
  float o1 = fmaxf(a.y * inv + bf2f(r.y) + b4.y, 0.f);
  float o2 = fmaxf(a.z * inv + bf2f(r.z) + b4.z, 0.f);
  float o3 = fmaxf(a.w * inv + bf2f(r.w) + b4.w, 0.f);
  h2[(size_t)i * 256 + f] = make_ushort4(f2bf(o0), f2bf(o1), f2bf(o2), f2bf(o3));
}

// ---------- layer3 combine + log_softmax: one wave per node ----------
__global__ void k_combine3(const unsigned short* __restrict__ Z3, const int* __restrict__ rp,
                           const int* __restrict__ col, const float* __restrict__ bias,
                           float* __restrict__ out) {
  int i = blockIdx.x * 4 + (threadIdx.x >> 6);
  int c = threadIdx.x & 63;
  int s = rp[i], e = rp[i + 1];
  float inv = 1.0f / (float)max(e - s, 1);
  float a = 0.f;
  for (int n = s; n < e; ++n) a += bf2f(Z3[(size_t)col[n] * 128 + c]);
  float v = a * inv + bf2f(Z3[(size_t)i * 128 + 64 + c]) + bias[c];
  float m = v;
#pragma unroll
  for (int o = 1; o < 64; o <<= 1) m = fmaxf(m, __shfl_xor(m, o, 64));
  float t = expf(v - m);
  float sum = t;
#pragma unroll
  for (int o = 1; o < 64; o <<= 1) sum += __shfl_xor(sum, o, 64);
  out[(size_t)i * 64 + c] = (v - m) - logf(sum);
}

// ---------- launch ----------
extern "C" void kernel_launch(void* const* d_in, const int* in_sizes, int n_in,
                              void* d_out, int out_size, void* d_ws, size_t ws_size,
                              hipStream_t stream) {
  const float* x   = (const float*)d_in[0];
  const int*   ei  = (const int*)d_in[1];
  const float* W1l = (const float*)d_in[2];
  const float* b1  = (const float*)d_in[3];
  const float* W1r = (const float*)d_in[4];
  const float* W2l = (const float*)d_in[5];
  const float* b2  = (const float*)d_in[6];
  const float* W2r = (const float*)d_in[7];
  const float* W3l = (const float*)d_in[8];
  const float* b3  = (const float*)d_in[9];
  const float* W3r = (const float*)d_in[10];

  const int Nn = 16000;
  const int E = in_sizes[1] / 2;

  char* p = (char*)d_ws;
  auto carve = [&](size_t bytes) {
    char* r = p;
    p += (bytes + 255) & ~(size_t)255;
    return r;
  };
  int* deg    = (int*)carve((size_t)Nn * 4);
  int* rp     = (int*)carve((size_t)(Nn + 1) * 4);
  int* cur    = (int*)carve((size_t)Nn * 4);
  int* flag   = (int*)carve(4);
  int* colidx = (int*)carve((size_t)E * 4);
  unsigned short* Wb = (unsigned short*)carve((size_t)2048 * 4096 * 2);  // weights, reused
  unsigned short* xm = (unsigned short*)carve((size_t)Nn * 1024 * 2);    // [root|mean]; later h2
  unsigned short* h1 = (unsigned short*)carve((size_t)Nn * 4096 * 2);
  unsigned short* Z2 = (unsigned short*)carve((size_t)Nn * 2048 * 2);
  unsigned short* Z3 = (unsigned short*)carve((size_t)Nn * 128 * 2);
  unsigned short* h2 = xm;  // xm dead after GEMM1

  size_t need = (size_t)(p - (char*)d_ws);
  if (ws_size < need) {
    k_sentinel<<<(out_size + 255) / 256, 256, 0, stream>>>((float*)d_out, out_size,
                                                           (float)(ws_size >> 20));
    return;
  }

  // CSR
  k_zero<<<(Nn + 255) / 256, 256, 0, stream>>>(deg, Nn);
  k_detect<<<1, 64, 0, stream>>>(ei, flag);
  k_degree<<<(E + 255) / 256, 256, 0, stream>>>(ei, E, flag, deg);
  k_scan<<<1, 256, 0, stream>>>(deg, rp, cur, Nn);
  k_fill<<<(E + 255) / 256, 256, 0, stream>>>(ei, E, flag, cur, colidx);

  // layer 1: A = [root | mean] (K=1024), B1 = [W1r^T | W1l^T] (4096 x 1024)
  k_cvtx<<<(Nn * 128 + 255) / 256, 256, 0, stream>>>((const float4*)x, (ushort4*)xm, Nn * 128);
  k_transW<<<dim3(4096 / 32, 512 / 32), 256, 0, stream>>>(W1r, Wb, 512, 4096, 1024, 0);
  k_transW<<<dim3(4096 / 32, 512 / 32), 256, 0, stream>>>(W1l, Wb, 512, 4096, 1024, 512);
  k_agg<<<Nn, 128, 0, stream>>>((ushort4*)xm, rp, colidx);
  k_gemm256<true, true><<<63 * 16, 512, 0, stream>>>(xm, Wb, b1, h1, Nn, 4096, 1024, 4);

  // layer 2 (post-agg): Z2 = h1 @ [W2l^T ; W2r^T]  (N=2048, K=4096)
  k_transW<<<dim3(1024 / 32, 4096 / 32), 256, 0, stream>>>(W2l, Wb, 4096, 1024, 4096, 0);
  k_transW<<<dim3(1024 / 32, 4096 / 32), 256, 0, stream>>>(W2r, Wb + (size_t)1024 * 4096, 4096,
                                                           1024, 4096, 0);
  k_gemm256<false, false><<<63 * 8, 512, 0, stream>>>(h1, Wb, nullptr, Z2, Nn, 2048, 4096, 3);
  k_combine2<<<Nn, 256, 0, stream>>>((const ushort4*)Z2, rp, colidx, b2, (ushort4*)h2);

  // layer 3 (post-agg, tiny): Z3 = h2 @ [W3l^T ; W3r^T]  (N=128, K=1024)
  k_transW<<<dim3(64 / 32, 1024 / 32), 256, 0, stream>>>(W3l, Wb, 1024, 64, 1024, 0);
  k_transW<<<dim3(64 / 32, 1024 / 32), 256, 0, stream>>>(W3r, Wb + (size_t)64 * 1024, 1024, 64,
                                                         1024, 0);
  k_gemm<2, false, false, false><<<dim3(125, 2), 256, 0, stream>>>(h2, nullptr, Wb, nullptr,
                                                                   nullptr, Z3, 128, 1024);
  k_combine3<<<Nn / 4, 256, 0, stream>>>(Z3, rp, colidx, b3, (float*)d_out);

  (void)n_in; (void)out_size;
}